// Round 9
// baseline (7443.195 us; speedup 1.0000x reference)
//
#include <hip/hip_runtime.h>
#include <stdint.h>

typedef unsigned int uint32;
typedef unsigned short u16;
typedef unsigned char u8;
typedef long long i64;
typedef __attribute__((ext_vector_type(4))) float f32x4;    // MFMA C/D frag

#define HASH_BITS 19
#define TABLE_SZ (1u << HASH_BITS)
#define HMASK (TABLE_SZ - 1u)
#define PI_D 3.141592653589793
#define NPTS 131072
#define NWB4 (4 * 512 * 512)          // fp8 bytes for W2..W5 = exactly 1 MiB

__device__ __forceinline__ u8 f2fp8(float f) {  // f32 -> e4m3fn (saturating, HW cvt)
    int r = __builtin_amdgcn_cvt_pk_fp8_f32(f, f, 0, false);
    return (u8)(r & 0xFF);
}

// floor(16 * 2^(l/3)) exactly as the f32 reference computes it
__device__ const float g_res[16] = {16.f,20.f,25.f,32.f,40.f,50.f,64.f,80.f,
                                    101.f,128.f,161.f,203.f,256.f,322.f,406.f,512.f};

// W2..W5 (512x512) -> fp8 e4m3 in ws (exactly 1 MiB), tiled so one wave B-frag
// load for (colgroup g, kstep kk) is ONE contiguous 512B block:
//   block[lane*8 + j] = W[col = g*16 + (lane&15)][k = kk*32 + (lane>>4)*8 + j]
__global__ void prep_weights(const float* __restrict__ W2, const float* __restrict__ W3,
                             const float* __restrict__ W4, const float* __restrict__ W5,
                             u8* __restrict__ wt8) {
    int pid = blockIdx.x * 256 + threadIdx.x;
    int e = pid * 2;                          // even element index
    if (e < NWB4) {
        int m = e >> 18;
        int rem = e & 262143;
        int n = rem >> 9, k = rem & 511;      // k even
        const float* W = (m == 0) ? W2 : (m == 1) ? W3 : (m == 2) ? W4 : W5;
        float v0 = W[k * 512 + n], v1 = W[(k + 1) * 512 + n];
        int g = n >> 4, r = n & 15, kk = k >> 5, kg = (k >> 3) & 3;
        int dst = m * 262144 + g * 8192 + kk * 512 + (kg * 16 + r) * 8 + (k & 7);
        int pk = __builtin_amdgcn_cvt_pk_fp8_f32(v0, v1, 0, false);
        *(u16*)(wt8 + dst) = (u16)(pk & 0xFFFF);
    }
}

__global__ void mask_kernel(const float* __restrict__ x, float* __restrict__ mout, int B) {
    int i = blockIdx.x * 256 + threadIdx.x;
    if (i >= B) return;
    constexpr float bmin[4] = {0.0f, (float)(-PI_D), (float)(0.5 * PI_D), (float)(-0.85 * PI_D)};
    constexpr float bmax[4] = {(float)(PI_D), (float)(PI_D), (float)(0.85 * PI_D), (float)(-0.5 * PI_D)};
    float4 v = ((const float4*)x)[i];
    bool ok = (v.x >= bmin[0]) && (v.x <= bmax[0]) &&
              (v.y >= bmin[1]) && (v.y <= bmax[1]) &&
              (v.z >= bmin[2]) && (v.z <= bmax[2]) &&
              (v.w >= bmin[3]) && (v.w <= bmax[3]);
    mout[i] = ok ? 1.0f : 0.0f;
}

// Phase A: one block = 64 points x 1 level, 8 waves, fp8 acts/weights, ~46KB LDS.
// __launch_bounds__(512, 4): VGPR budget 128 — R7/R8's (512,6) capped at ~85 and
// SPILLED the 64-f32 accumulator to scratch (VGPR_Count=40, 385MB writes). Never
// cap below the accumulator footprint.
__global__ __launch_bounds__(512, 4)
void mlp_kernel(const float* __restrict__ x,
                const float* __restrict__ W1, const float* __restrict__ b1,
                const u8* __restrict__ wt8, const float* __restrict__ W6,
                const float* __restrict__ b2, const float* __restrict__ b3,
                const float* __restrict__ b4, const float* __restrict__ b5,
                const float* __restrict__ b6,
                u8* __restrict__ stage_base, int stage_stride,
                int level, int p0) {
    __shared__ u8 act[64 * 512];           // 32KB fp8 activations (XOR-swizzled 8B units)
    __shared__ float xsh[64 * 4];          // 1KB
    __shared__ float swsh[64 * 17];        // 4.3KB logits
    __shared__ u8 w6lds[16 * 512];         // 8KB fp8 W6, frag-tiled

    const int tid = threadIdx.x;
    const int lane = tid & 63;
    const int wv = tid >> 6;               // wave 0..7
    const int ptile = blockIdx.x;
    const float res = g_res[level];

    if (tid < 256) xsh[tid] = x[(size_t)(p0 + ptile * 64) * 4 + tid];
    // build w6lds: byte d -> W6[(kk*32+kg*8+j)*16 + jc], d = kk*512+(kg*16+jc)*8+j
    {
        int base = tid * 16;
#pragma unroll
        for (int i = 0; i < 16; ++i) {
            int d = base + i;
            int kk = d >> 9, w = d & 511, p16 = w >> 3, j = d & 7;
            int kg = p16 >> 4, jc = p16 & 15;
            w6lds[d] = f2fp8(W6[(kk * 32 + kg * 8 + j) * 16 + jc]);
        }
    }
    __syncthreads();

    // ---- layer 1: feat=[res,x] (K=5) -> 512, VALU. thread t owns column n=t.
    {
        const int n = tid;
        float w0 = W1[n], w1 = W1[512 + n], w2 = W1[1024 + n],
              w3 = W1[1536 + n], w4 = W1[2048 + n];
        float base = fmaf(res, w0, b1[n]);
        const int u0 = n >> 3, nlo = n & 7;
        for (int p = 0; p < 64; ++p) {
            float v = base;
            v = fmaf(xsh[p * 4 + 0], w1, v);
            v = fmaf(xsh[p * 4 + 1], w2, v);
            v = fmaf(xsh[p * 4 + 2], w3, v);
            v = fmaf(xsh[p * 4 + 3], w4, v);
            v = fmaxf(v, 0.0f);
            act[p * 512 + ((u0 ^ (p & 7)) << 3) + nlo] = f2fp8(v);
        }
    }
    __syncthreads();

    // ---- layers 2..5: 512x512 fp8 MFMA. wave = 64 rows x 64 cols (acc[4][4]).
    const int row = lane & 15;
    const int kg = lane >> 4;
    for (int ly = 0; ly < 4; ++ly) {
        const float* bias = (ly == 0) ? b2 : (ly == 1) ? b3 : (ly == 2) ? b4 : b5;
        f32x4 acc[4][4];
#pragma unroll
        for (int rt = 0; rt < 4; ++rt)
#pragma unroll
            for (int ct = 0; ct < 4; ++ct) acc[rt][ct] = (f32x4){0.f, 0.f, 0.f, 0.f};

#pragma unroll 4
        for (int kk = 0; kk < 16; ++kk) {
            const int k0 = kk * 32 + kg * 8;
            i64 a[4], b[4];
#pragma unroll
            for (int rt = 0; rt < 4; ++rt) {
                int r = rt * 16 + row;
                a[rt] = *(const i64*)&act[r * 512 + (((k0 >> 3) ^ (r & 7)) << 3)];
            }
#pragma unroll
            for (int ct = 0; ct < 4; ++ct)   // ONE contiguous 512B wave load
                b[ct] = *(const i64*)&wt8[ly * 262144 + (wv * 4 + ct) * 8192 + kk * 512 + lane * 8];
#pragma unroll
            for (int rt = 0; rt < 4; ++rt)
#pragma unroll
                for (int ct = 0; ct < 4; ++ct)
                    acc[rt][ct] = __builtin_amdgcn_mfma_f32_16x16x32_fp8_fp8(a[rt], b[ct], acc[rt][ct], 0, 0, 0);
        }
        __syncthreads();
        // epilogue: bias + relu -> act fp8. C/D: col=lane&15, rowreg=kg*4+q.
#pragma unroll
        for (int ct = 0; ct < 4; ++ct) {
            int col = wv * 64 + ct * 16 + row;
            float bv = bias[col];
            int ucol = col >> 3, clo = col & 7;
#pragma unroll
            for (int rt = 0; rt < 4; ++rt)
#pragma unroll
                for (int q = 0; q < 4; ++q) {
                    int rg = rt * 16 + kg * 4 + q;
                    float v = fmaxf(acc[rt][ct][q] + bv, 0.0f);
                    act[rg * 512 + ((ucol ^ (rg & 7)) << 3) + clo] = f2fp8(v);
                }
        }
        __syncthreads();
    }

    // ---- layer 6: 512 -> 16 logits via MFMA on waves 0..3 (LDS weights)
    if (wv < 4) {
        f32x4 acc = {0.f, 0.f, 0.f, 0.f};
        const int r = wv * 16 + row;
#pragma unroll 4
        for (int kk = 0; kk < 16; ++kk) {
            int k0 = kk * 32 + kg * 8;
            i64 a = *(const i64*)&act[r * 512 + (((k0 >> 3) ^ (r & 7)) << 3)];
            i64 b = *(const i64*)&w6lds[kk * 512 + lane * 8];
            acc = __builtin_amdgcn_mfma_f32_16x16x32_fp8_fp8(a, b, acc, 0, 0, 0);
        }
        float bv = b6[row];
#pragma unroll
        for (int q = 0; q < 4; ++q) {
            int rg = wv * 16 + kg * 4 + q;
            swsh[rg * 17 + row] = acc[q] + bv;
        }
    }
    __syncthreads();

    // ---- softmax over 16 -> u8 fixed-point -> stage (threads 0..63)
    if (tid < 64) {
        float zv[16];
        float m = -1e30f;
#pragma unroll
        for (int j = 0; j < 16; ++j) { zv[j] = swsh[tid * 17 + j]; m = fmaxf(m, zv[j]); }
        float s = 0.f;
#pragma unroll
        for (int j = 0; j < 16; ++j) { zv[j] = expf(zv[j] - m); s += zv[j]; }
        float inv = 255.0f / s;               // |w - q/255| <= 1/510 -> out err ~3e-6
        uint32 pk[4];
#pragma unroll
        for (int q = 0; q < 4; ++q) {
            uint32 v = 0;
#pragma unroll
            for (int j = 0; j < 4; ++j) {
                uint32 b = (uint32)(zv[q * 4 + j] * inv + 0.5f);
                v |= (b & 255u) << (j * 8);
            }
            pk[q] = v;
        }
        *(uint4*)(stage_base + (size_t)(ptile * 64 + tid) * stage_stride) =
            make_uint4(pk[0], pk[1], pk[2], pk[3]);
    }
}

// Phase B: pure gather for one level (chunk). Table (4MB) owns the per-XCD L2.
__global__ __launch_bounds__(256, 8)
void gather_kernel(const float* __restrict__ x, const float* __restrict__ tables,
                   const u8* __restrict__ stage_base, int stage_stride,
                   float* __restrict__ out, int level, int p0) {
    const int ploc = blockIdx.x * 256 + threadIdx.x;
    const int p = p0 + ploc;
    const float res = g_res[level];
    constexpr float bmin[4] = {0.0f, (float)(-PI_D), (float)(0.5 * PI_D), (float)(-0.85 * PI_D)};
    constexpr float bmax[4] = {(float)(PI_D), (float)(PI_D), (float)(0.85 * PI_D), (float)(-0.5 * PI_D)};
    constexpr uint32 primes[4] = {1u, 2654435761u, 805459861u, 3674653429u};

    float4 xv4 = ((const float4*)x)[p];
    float xd[4] = {xv4.x, xv4.y, xv4.z, xv4.w};
    uint32 ca[4], cb[4];
#pragma unroll
    for (int d = 0; d < 4; ++d) {
        float xc = fminf(fmaxf(xd[d], bmin[d]), bmax[d]);
        float g = (bmax[d] - bmin[d]) / res;
        float t = (xc - bmin[d]) / g;
        int bl = (int)floorf(t);
        ca[d] = (uint32)bl * primes[d];
        cb[d] = (uint32)(bl + 1) * primes[d];
    }
    uint4 wp = *(const uint4*)(stage_base + (size_t)ploc * stage_stride);
    uint32 wu[4] = {wp.x, wp.y, wp.z, wp.w};

    const float* tb = tables + (size_t)level * TABLE_SZ * 2;
    float s0 = 0.f, s1 = 0.f;
#pragma unroll
    for (int v = 0; v < 16; ++v) {
        uint32 h = ((v & 8) ? cb[0] : ca[0]) ^ ((v & 4) ? cb[1] : ca[1]) ^
                   ((v & 2) ? cb[2] : ca[2]) ^ ((v & 1) ? cb[3] : ca[3]);
        float2 e = *(const float2*)(tb + (size_t)(h & HMASK) * 2);
        float wgt = (float)((wu[v >> 2] >> ((v & 3) * 8)) & 255u) * (1.0f / 255.0f);
        s0 = fmaf(wgt, e.x, s0);
        s1 = fmaf(wgt, e.y, s1);
    }
    float* o = out + (size_t)p * 32 + level * 2;
    o[0] = s0;
    o[1] = s1;
}

extern "C" void kernel_launch(void* const* d_in, const int* in_sizes, int n_in,
                              void* d_out, int out_size, void* d_ws, size_t ws_size,
                              hipStream_t stream) {
    const float* x      = (const float*)d_in[0];
    const float* tables = (const float*)d_in[1];
    const float* W1 = (const float*)d_in[2];
    const float* b1 = (const float*)d_in[3];
    const float* W2 = (const float*)d_in[4];
    const float* b2 = (const float*)d_in[5];
    const float* W3 = (const float*)d_in[6];
    const float* b3 = (const float*)d_in[7];
    const float* W4 = (const float*)d_in[8];
    const float* b4 = (const float*)d_in[9];
    const float* W5 = (const float*)d_in[10];
    const float* b5 = (const float*)d_in[11];
    const float* W6 = (const float*)d_in[12];
    const float* b6 = (const float*)d_in[13];

    const int B = in_sizes[0] / 4;          // 131072
    u8* wt8 = (u8*)d_ws;                    // exactly 1 MiB fp8 panel (W2..W5)
    u8* outb = (u8*)d_out;                  // out rows: 128B per point
    u8* maskreg = outb + (size_t)B * 128;   // 512KB, free until mask_kernel

    prep_weights<<<(NWB4 / 2 + 255) / 256, 256, 0, stream>>>(W2, W3, W4, W5, wt8);

    // Levels 0..13: stage u8 weights in each point's own out row, bytes 112..127
    // (slots 28-31 = levels 14,15 outputs — unwritten until the loops below).
    for (int level = 0; level < 14; ++level) {
        mlp_kernel<<<dim3(NPTS / 64), 512, 0, stream>>>(
            x, W1, b1, wt8, W6, b2, b3, b4, b5, b6,
            outb + 112, 128, level, 0);
        gather_kernel<<<dim3(NPTS / 256), 256, 0, stream>>>(
            x, tables, outb + 112, 128, (float*)d_out, level, 0);
    }
    // Levels 14,15: stage in the mask region (512KB = 32K pts), 4 chunks each.
    for (int level = 14; level < 16; ++level) {
        for (int c = 0; c < 4; ++c) {
            int p0 = c * 32768;
            mlp_kernel<<<dim3(32768 / 64), 512, 0, stream>>>(
                x, W1, b1, wt8, W6, b2, b3, b4, b5, b6,
                maskreg, 16, level, p0);
            gather_kernel<<<dim3(32768 / 256), 256, 0, stream>>>(
                x, tables, maskreg, 16, (float*)d_out, level, p0);
        }
    }
    mask_kernel<<<(B + 255) / 256, 256, 0, stream>>>(x, (float*)d_out + (size_t)B * 32, B);
}

// Round 10
// 3613.638 us; speedup vs baseline: 2.0598x; 2.0598x over previous
//
#include <hip/hip_runtime.h>
#include <stdint.h>

typedef unsigned int uint32;
typedef unsigned short u16;
typedef unsigned char u8;
typedef long long i64;
typedef unsigned long long u64;
typedef __attribute__((ext_vector_type(4))) float f32x4;    // MFMA C/D frag

#define HASH_BITS 19
#define TABLE_SZ (1u << HASH_BITS)
#define HMASK (TABLE_SZ - 1u)
#define PI_D 3.141592653589793
#define NPTS 131072
#define NWB4 (4 * 512 * 512)          // fp8 bytes for W2..W5 = exactly 1 MiB

__device__ __forceinline__ u8 f2fp8(float f) {  // f32 -> e4m3fn (saturating, HW cvt)
    int r = __builtin_amdgcn_cvt_pk_fp8_f32(f, f, 0, false);
    return (u8)(r & 0xFF);
}

// floor(16 * 2^(l/3)) exactly as the f32 reference computes it
__device__ const float g_res[16] = {16.f,20.f,25.f,32.f,40.f,50.f,64.f,80.f,
                                    101.f,128.f,161.f,203.f,256.f,322.f,406.f,512.f};

// W2..W5 (512x512) -> fp8 e4m3 in ws (exactly 1 MiB), tiled so one wave A-frag
// load for (n-group g, kstep kk) is ONE contiguous 512B block:
//   block[lane*8 + j] = W[col n = g*16 + (lane&15)][k = kk*32 + (lane>>4)*8 + j]
__global__ void prep_weights(const float* __restrict__ W2, const float* __restrict__ W3,
                             const float* __restrict__ W4, const float* __restrict__ W5,
                             u8* __restrict__ wt8) {
    int pid = blockIdx.x * 256 + threadIdx.x;
    int e = pid * 2;                          // even element index
    if (e < NWB4) {
        int m = e >> 18;
        int rem = e & 262143;
        int n = rem >> 9, k = rem & 511;      // k even
        const float* W = (m == 0) ? W2 : (m == 1) ? W3 : (m == 2) ? W4 : W5;
        float v0 = W[k * 512 + n], v1 = W[(k + 1) * 512 + n];
        int g = n >> 4, r = n & 15, kk = k >> 5, kg = (k >> 3) & 3;
        int dst = m * 262144 + g * 8192 + kk * 512 + (kg * 16 + r) * 8 + (k & 7);
        int pk = __builtin_amdgcn_cvt_pk_fp8_f32(v0, v1, 0, false);
        *(u16*)(wt8 + dst) = (u16)(pk & 0xFFFF);
    }
}

__global__ void mask_kernel(const float* __restrict__ x, float* __restrict__ mout, int B) {
    int i = blockIdx.x * 256 + threadIdx.x;
    if (i >= B) return;
    constexpr float bmin[4] = {0.0f, (float)(-PI_D), (float)(0.5 * PI_D), (float)(-0.85 * PI_D)};
    constexpr float bmax[4] = {(float)(PI_D), (float)(PI_D), (float)(0.85 * PI_D), (float)(-0.5 * PI_D)};
    float4 v = ((const float4*)x)[i];
    bool ok = (v.x >= bmin[0]) && (v.x <= bmax[0]) &&
              (v.y >= bmin[1]) && (v.y <= bmax[1]) &&
              (v.z >= bmin[2]) && (v.z <= bmax[2]) &&
              (v.w >= bmin[3]) && (v.w <= bmax[3]);
    mout[i] = ok ? 1.0f : 0.0f;
}

// One block = 64 points x 1 level, 8 waves, fp8 everywhere, ~62KB LDS (2/CU).
// MFMA operand order: A = weights (M=n), B = activations (N=points) so
// D[row=n][col=point] -> each thread's 4 acc values are 4 CONSECUTIVE n ->
// epilogue = 2x cvt_pk byte-sel + one ds_write_b32.
__global__ __launch_bounds__(512, 4)
void fused_mlp(const float* __restrict__ x, const float* __restrict__ tables,
               const float* __restrict__ W1, const float* __restrict__ b1,
               const u8* __restrict__ wt8, const float* __restrict__ W6,
               const float* __restrict__ b2, const float* __restrict__ b3,
               const float* __restrict__ b4, const float* __restrict__ b5,
               const float* __restrict__ b6, float* __restrict__ out, int level) {
    __shared__ u8 act[64 * 512];           // 32KB fp8 activations [pt][k], XOR-swizzled 8B units
    __shared__ u8 w1lds[32 * 512];         // 16KB fp8 W1' frags (K=32 padded, row0 pre-scaled x512)
    __shared__ u8 w6lds[16 * 512];         // 8KB fp8 W6 frags
    __shared__ float xsh[64 * 4];          // 1KB
    __shared__ float swsh[64 * 17];        // 4.3KB logits -> softmax weights

    const int tid = threadIdx.x;
    const int lane = tid & 63;
    const int wv = tid >> 6;               // wave 0..7
    const int ptile = blockIdx.x;
    const float res = g_res[level];
    const int lrow = lane & 15;            // point-within-tile / n-within-tile selector
    const int kg = lane >> 4;              // k-group 0..3

    if (tid < 256) xsh[tid] = x[(size_t)ptile * 256 + tid];
    // build w1lds: byte d -> W1'[k][n], n=(d>>9)*16+((d&511)>>3 &15), k=(((d&511)>>3)>>4)*8+(d&7)
    {
        int base = tid * 32;
#pragma unroll
        for (int i = 0; i < 32; ++i) {
            int d = base + i;
            int g = d >> 9, w = d & 511, l = w >> 3, j = d & 7;
            int n = g * 16 + (l & 15), k = (l >> 4) * 8 + j;
            float v = (k == 0) ? W1[n] * 512.0f : (k <= 4 ? W1[k * 512 + n] : 0.0f);
            w1lds[d] = f2fp8(v);
        }
    }
    // build w6lds: byte d -> W6[k][n], n=(d&511)>>3 &15, k=(d>>9)*32+(((d&511)>>3)>>4)*8+(d&7)
    {
        int base = tid * 16;
#pragma unroll
        for (int i = 0; i < 16; ++i) {
            int d = base + i;
            int kk = d >> 9, w = d & 511, l = w >> 3, j = d & 7;
            int n = l & 15, k = kk * 32 + (l >> 4) * 8 + j;
            w6lds[d] = f2fp8(W6[k * 16 + n]);
        }
    }
    __syncthreads();

    f32x4 acc[4][4];                       // [point-tile rt][n-tile ct]
#pragma unroll
    for (int rt = 0; rt < 4; ++rt)
#pragma unroll
        for (int ct = 0; ct < 4; ++ct) acc[rt][ct] = (f32x4){0.f, 0.f, 0.f, 0.f};

    // ---- layer 1 as MFMA: A = W1' (16n x 32k), B = feat (32k x 16pt), 1 k-step.
    {
        float rs = res * (1.0f / 512.0f);
        i64 bfeat[4];
#pragma unroll
        for (int rt = 0; rt < 4; ++rt) {
            float4 xv = *(const float4*)&xsh[(rt * 16 + lrow) * 4];
            uint32 lo = __builtin_amdgcn_cvt_pk_fp8_f32(rs, xv.x, 0, false);
            lo = __builtin_amdgcn_cvt_pk_fp8_f32(xv.y, xv.z, lo, true);
            uint32 hi = __builtin_amdgcn_cvt_pk_fp8_f32(xv.w, 0.0f, 0, false);
            u64 f = ((u64)hi << 32) | lo;
            bfeat[rt] = (kg == 0) ? (i64)f : (i64)0;   // only k=0..7 nonzero
        }
#pragma unroll
        for (int ct = 0; ct < 4; ++ct) {
            i64 a1 = *(const i64*)&w1lds[(wv * 4 + ct) * 512 + lane * 8];
#pragma unroll
            for (int rt = 0; rt < 4; ++rt)
                acc[rt][ct] = __builtin_amdgcn_mfma_f32_16x16x32_fp8_fp8(a1, bfeat[rt], acc[rt][ct], 0, 0, 0);
        }
        // epilogue: bias+relu -> act. D: col=lane&15=pt, rows = kg*4+q = n in tile.
#pragma unroll
        for (int ct = 0; ct < 4; ++ct) {
            int n0 = wv * 64 + ct * 16 + kg * 4;
            float4 bv = *(const float4*)&b1[n0];
            int u = n0 >> 3, lo2 = n0 & 4;
#pragma unroll
            for (int rt = 0; rt < 4; ++rt) {
                int pt = rt * 16 + lrow;
                float v0 = fmaxf(acc[rt][ct][0] + bv.x, 0.f);
                float v1 = fmaxf(acc[rt][ct][1] + bv.y, 0.f);
                float v2 = fmaxf(acc[rt][ct][2] + bv.z, 0.f);
                float v3 = fmaxf(acc[rt][ct][3] + bv.w, 0.f);
                uint32 wrd = __builtin_amdgcn_cvt_pk_fp8_f32(v0, v1, 0, false);
                wrd = __builtin_amdgcn_cvt_pk_fp8_f32(v2, v3, wrd, true);
                *(uint32*)&act[pt * 512 + ((u ^ (pt & 7)) << 3) + lo2] = wrd;
            }
        }
    }
    __syncthreads();

    // ---- layers 2..5: A = weight frags (global, L2), B = act frags (LDS).
    for (int ly = 0; ly < 4; ++ly) {
        const float* bias = (ly == 0) ? b2 : (ly == 1) ? b3 : (ly == 2) ? b4 : b5;
#pragma unroll
        for (int rt = 0; rt < 4; ++rt)
#pragma unroll
            for (int ct = 0; ct < 4; ++ct) acc[rt][ct] = (f32x4){0.f, 0.f, 0.f, 0.f};

#pragma unroll
        for (int kk = 0; kk < 16; ++kk) {
            i64 aw[4], ba[4];
#pragma unroll
            for (int ct = 0; ct < 4; ++ct)   // ONE contiguous 512B wave load
                aw[ct] = *(const i64*)&wt8[ly * 262144 + (wv * 4 + ct) * 8192 + kk * 512 + lane * 8];
#pragma unroll
            for (int rt = 0; rt < 4; ++rt) {
                int pt = rt * 16 + lrow;
                ba[rt] = *(const i64*)&act[pt * 512 + (((kk * 4 + kg) ^ (pt & 7)) << 3)];
            }
#pragma unroll
            for (int rt = 0; rt < 4; ++rt)
#pragma unroll
                for (int ct = 0; ct < 4; ++ct)
                    acc[rt][ct] = __builtin_amdgcn_mfma_f32_16x16x32_fp8_fp8(aw[ct], ba[rt], acc[rt][ct], 0, 0, 0);
        }
        __syncthreads();   // all waves done reading act
#pragma unroll
        for (int ct = 0; ct < 4; ++ct) {
            int n0 = wv * 64 + ct * 16 + kg * 4;
            float4 bv = *(const float4*)&bias[n0];
            int u = n0 >> 3, lo2 = n0 & 4;
#pragma unroll
            for (int rt = 0; rt < 4; ++rt) {
                int pt = rt * 16 + lrow;
                float v0 = fmaxf(acc[rt][ct][0] + bv.x, 0.f);
                float v1 = fmaxf(acc[rt][ct][1] + bv.y, 0.f);
                float v2 = fmaxf(acc[rt][ct][2] + bv.z, 0.f);
                float v3 = fmaxf(acc[rt][ct][3] + bv.w, 0.f);
                uint32 wrd = __builtin_amdgcn_cvt_pk_fp8_f32(v0, v1, 0, false);
                wrd = __builtin_amdgcn_cvt_pk_fp8_f32(v2, v3, wrd, true);
                *(uint32*)&act[pt * 512 + ((u ^ (pt & 7)) << 3) + lo2] = wrd;
            }
        }
        __syncthreads();
    }

    // ---- layer 6: 512 -> 16 logits. waves 0..3, wave wv handles point-tile wv.
    if (wv < 4) {
        f32x4 a6 = {0.f, 0.f, 0.f, 0.f};
        const int pt = wv * 16 + lrow;
#pragma unroll
        for (int kk = 0; kk < 16; ++kk) {
            i64 aw = *(const i64*)&w6lds[kk * 512 + lane * 8];
            i64 ba = *(const i64*)&act[pt * 512 + (((kk * 4 + kg) ^ (pt & 7)) << 3)];
            a6 = __builtin_amdgcn_mfma_f32_16x16x32_fp8_fp8(aw, ba, a6, 0, 0, 0);
        }
        int n0 = kg * 4;
        float4 bv = *(const float4*)&b6[n0];
        swsh[pt * 17 + n0 + 0] = a6[0] + bv.x;
        swsh[pt * 17 + n0 + 1] = a6[1] + bv.y;
        swsh[pt * 17 + n0 + 2] = a6[2] + bv.z;
        swsh[pt * 17 + n0 + 3] = a6[3] + bv.w;
    }
    __syncthreads();

    // ---- softmax over 16 (threads 0..63, one point each)
    if (tid < 64) {
        float zv[16];
        float m = -1e30f;
#pragma unroll
        for (int j = 0; j < 16; ++j) { zv[j] = swsh[tid * 17 + j]; m = fmaxf(m, zv[j]); }
        float s = 0.f;
#pragma unroll
        for (int j = 0; j < 16; ++j) { zv[j] = expf(zv[j] - m); s += zv[j]; }
        float inv = 1.0f / s;
#pragma unroll
        for (int j = 0; j < 16; ++j) swsh[tid * 17 + j] = zv[j] * inv;
    }
    __syncthreads();

    // ---- hash gather + weighted sum: 8 threads/point, 2 corners each.
    {
        constexpr float bmin[4] = {0.0f, (float)(-PI_D), (float)(0.5 * PI_D), (float)(-0.85 * PI_D)};
        constexpr float bmax[4] = {(float)(PI_D), (float)(PI_D), (float)(0.85 * PI_D), (float)(-0.5 * PI_D)};
        constexpr uint32 primes[4] = {1u, 2654435761u, 805459861u, 3674653429u};
        const int p = tid >> 3;
        const int pr = tid & 7;
        uint32 ca[4], cb[4];
#pragma unroll
        for (int d = 0; d < 4; ++d) {
            float xv = xsh[p * 4 + d];
            float xc = fminf(fmaxf(xv, bmin[d]), bmax[d]);
            float g = (bmax[d] - bmin[d]) / res;
            float t = (xc - bmin[d]) / g;
            int bl = (int)floorf(t);
            ca[d] = (uint32)bl * primes[d];
            cb[d] = (uint32)(bl + 1) * primes[d];
        }
        float s0 = 0.f, s1 = 0.f;
        const float* tb = tables + (size_t)level * TABLE_SZ * 2;
#pragma unroll
        for (int vv = 0; vv < 2; ++vv) {
            int v = pr * 2 + vv;
            uint32 h = ((v & 8) ? cb[0] : ca[0]) ^ ((v & 4) ? cb[1] : ca[1]) ^
                       ((v & 2) ? cb[2] : ca[2]) ^ ((v & 1) ? cb[3] : ca[3]);
            float2 e = *(const float2*)(tb + (size_t)(h & HMASK) * 2);
            float wgt = swsh[p * 17 + v];
            s0 = fmaf(wgt, e.x, s0);
            s1 = fmaf(wgt, e.y, s1);
        }
#pragma unroll
        for (int sft = 1; sft < 8; sft <<= 1) {
            s0 += __shfl_xor(s0, sft, 64);
            s1 += __shfl_xor(s1, sft, 64);
        }
        if (pr == 0) {
            float* o = out + (size_t)(ptile * 64 + p) * 32 + level * 2;
            __builtin_nontemporal_store(s0, o);
            __builtin_nontemporal_store(s1, o + 1);
        }
    }
}

extern "C" void kernel_launch(void* const* d_in, const int* in_sizes, int n_in,
                              void* d_out, int out_size, void* d_ws, size_t ws_size,
                              hipStream_t stream) {
    const float* x      = (const float*)d_in[0];
    const float* tables = (const float*)d_in[1];
    const float* W1 = (const float*)d_in[2];
    const float* b1 = (const float*)d_in[3];
    const float* W2 = (const float*)d_in[4];
    const float* b2 = (const float*)d_in[5];
    const float* W3 = (const float*)d_in[6];
    const float* b3 = (const float*)d_in[7];
    const float* W4 = (const float*)d_in[8];
    const float* b4 = (const float*)d_in[9];
    const float* W5 = (const float*)d_in[10];
    const float* b5 = (const float*)d_in[11];
    const float* W6 = (const float*)d_in[12];
    const float* b6 = (const float*)d_in[13];

    const int B = in_sizes[0] / 4;          // 131072
    u8* wt8 = (u8*)d_ws;                    // exactly 1 MiB fp8 panel (W2..W5)

    prep_weights<<<(NWB4 / 2 + 255) / 256, 256, 0, stream>>>(W2, W3, W4, W5, wt8);

    for (int level = 0; level < 16; ++level) {
        fused_mlp<<<dim3(NPTS / 64), 512, 0, stream>>>(
            x, tables, W1, b1, wt8, W6, b2, b3, b4, b5, b6, (float*)d_out, level);
    }
    mask_kernel<<<(B + 255) / 256, 256, 0, stream>>>(x, (float*)d_out + (size_t)B * 32, B);
}